// Round 3
// baseline (201.522 us; speedup 1.0000x reference)
//
#include <hip/hip_runtime.h>
#include <math.h>

#define N_ROWS 131072
#define U2_OFF 4096   // floats: Sw = ws[0..4095] (16x256), U2 = ws[4096..4351] (16x16)
#define NR 32         // rows per (single-wave) block
#define ZSTRIDE 20    // LDS row stride in floats (80B, 16B-aligned, spreads banks)

// ---------------- stage-1 builder: 8-qubit state, 4 amps/lane ----------------
__device__ __forceinline__ void ry8(float v[4], int lane, int bp, float c, float s) {
  if (bp == 0) {
    float n0 = fmaf(s, v[1], c * v[0]);
    float n1 = fmaf(-s, v[0], c * v[1]);
    float n2 = fmaf(s, v[3], c * v[2]);
    float n3 = fmaf(-s, v[2], c * v[3]);
    v[0] = n0; v[1] = n1; v[2] = n2; v[3] = n3;
  } else if (bp == 1) {
    float n0 = fmaf(s, v[2], c * v[0]);
    float n2 = fmaf(-s, v[0], c * v[2]);
    float n1 = fmaf(s, v[3], c * v[1]);
    float n3 = fmaf(-s, v[1], c * v[3]);
    v[0] = n0; v[1] = n1; v[2] = n2; v[3] = n3;
  } else {
    int lm = 1 << (bp - 2);
    float sgn = ((lane >> (bp - 2)) & 1) ? -s : s;
#pragma unroll
    for (int k = 0; k < 4; ++k) {
      float o = __shfl_xor(v[k], lm);
      v[k] = fmaf(sgn, o, c * v[k]);
    }
  }
}

__device__ __forceinline__ void cnot8(float v[4], int lane, int cb, int tb) {
  if (cb >= 2 && tb >= 2) {
    int lm = 1 << (tb - 2);
    bool hc = (lane >> (cb - 2)) & 1;
#pragma unroll
    for (int k = 0; k < 4; ++k) {
      float o = __shfl_xor(v[k], lm);
      v[k] = hc ? o : v[k];
    }
  } else if (cb >= 2) {
    bool hc = (lane >> (cb - 2)) & 1;
    if (tb == 0) {
      float n0 = hc ? v[1] : v[0], n1 = hc ? v[0] : v[1];
      float n2 = hc ? v[3] : v[2], n3 = hc ? v[2] : v[3];
      v[0] = n0; v[1] = n1; v[2] = n2; v[3] = n3;
    } else {
      float n0 = hc ? v[2] : v[0], n2 = hc ? v[0] : v[2];
      float n1 = hc ? v[3] : v[1], n3 = hc ? v[1] : v[3];
      v[0] = n0; v[1] = n1; v[2] = n2; v[3] = n3;
    }
  } else if (tb >= 2) {
    int lm = 1 << (tb - 2);
#pragma unroll
    for (int k = 0; k < 4; ++k) {
      float o = __shfl_xor(v[k], lm);
      if ((k >> cb) & 1) v[k] = o;
    }
  } else {
    if (cb == 0) { float t = v[1]; v[1] = v[3]; v[3] = t; }
    else         { float t = v[2]; v[2] = v[3]; v[3] = t; }
  }
}

// ---------------- stage-2 builder: full 16-dim state in registers ----------------
template <int BP>
__device__ __forceinline__ void ry16t(float* w, float c, float s) {
#pragma unroll
  for (int i = 0; i < 16; ++i) {
    if (((i >> BP) & 1) == 0) {
      const int j = i | (1 << BP);
      float a = w[i], b = w[j];
      w[i] = fmaf(s, b, c * a);
      w[j] = fmaf(-s, a, c * b);
    }
  }
}
__device__ __forceinline__ void ry16(float* w, int bp, float c, float s) {
  switch (bp) {
    case 0: ry16t<0>(w, c, s); break;
    case 1: ry16t<1>(w, c, s); break;
    case 2: ry16t<2>(w, c, s); break;
    default: ry16t<3>(w, c, s); break;
  }
}
template <int CB, int TB>
__device__ __forceinline__ void cnot16t(float* w) {
#pragma unroll
  for (int i = 0; i < 16; ++i) {
    if (((i >> CB) & 1) == 1 && ((i >> TB) & 1) == 0) {
      const int j = i | (1 << TB);
      float t = w[i]; w[i] = w[j]; w[j] = t;
    }
  }
}
__device__ __forceinline__ void cnot16(float* w, int cb, int tb) {
#define CC(a, b) if (cb == a && tb == b) { cnot16t<a, b>(w); return; }
  CC(0,1) CC(0,2) CC(0,3) CC(1,0) CC(1,2) CC(1,3)
  CC(2,0) CC(2,1) CC(2,3) CC(3,0) CC(3,1) CC(3,2)
#undef CC
}

__global__ void build_states_kernel(const float* __restrict__ thc,
                                    const float* __restrict__ th2,
                                    float* __restrict__ ws) {
  const int blk = blockIdx.x;
  const int lane = threadIdx.x;  // 64 threads
  if (blk < 16) {
    const float* th = thc + blk * 72;
    float v[4] = {0.f, 0.f, 0.f, 0.f};
    if (lane == 0) v[0] = 1.f;
    int p = 0;
    for (int m = 0; m < 8; ++m) {
#pragma unroll
      for (int q = 0; q < 8; ++q) {
        float a = 0.5f * th[p + q];
        ry8(v, lane, 7 - q, cosf(a), sinf(a));
      }
      p += 8;
#pragma unroll
      for (int q = 0; q < 8; ++q) {
        int tgt = (m % 2 == 0) ? ((q + 1) & 7) : ((q + 7) & 7);
        cnot8(v, lane, 7 - q, 7 - tgt);
      }
    }
#pragma unroll
    for (int q = 0; q < 8; ++q) {
      float a = 0.5f * th[p + q];
      ry8(v, lane, 7 - q, cosf(a), sinf(a));
    }
    float4* swv = (float4*)ws;
    swv[blk * 64 + lane] = make_float4(v[0], v[1], v[2], v[3]);
  } else {
    float w[16];
#pragma unroll
    for (int j = 0; j < 16; ++j) w[j] = (j == lane) ? 1.f : 0.f;
    int p = 0;
    for (int m = 0; m < 8; ++m) {
#pragma unroll
      for (int q = 0; q < 4; ++q) {
        float a = 0.5f * th2[p + q];
        ry16(w, 3 - q, cosf(a), sinf(a));
      }
      p += 4;
#pragma unroll
      for (int q = 0; q < 4; ++q) {
        int tgt = (m % 2 == 0) ? ((q + 1) & 3) : ((q + 3) & 3);
        cnot16(w, 3 - q, 3 - tgt);
      }
    }
#pragma unroll
    for (int q = 0; q < 4; ++q) {
      float a = 0.5f * th2[p + q];
      ry16(w, 3 - q, cosf(a), sinf(a));
    }
    if (lane < 16) {
      float* u2 = ws + U2_OFF;
#pragma unroll
      for (int j = 0; j < 16; ++j) u2[lane * 16 + j] = w[j];
    }
  }
}

__device__ __forceinline__ float silu_g(float z) {
  float v = z / (1.f + __expf(-z));
  return isfinite(v) ? v : 0.f;
}

// 16 FMAs of one 4-float4 chunk against swr[k..k+3], into 4 accumulator chains
#define CHUNK(b0, b1, b2, b3, k)                                               \
  z0 = fmaf(b0.x, swr[k].x, z0);     z1 = fmaf(b0.y, swr[k].y, z1);            \
  z2 = fmaf(b0.z, swr[k].z, z2);     z3 = fmaf(b0.w, swr[k].w, z3);            \
  z0 = fmaf(b1.x, swr[(k)+1].x, z0); z1 = fmaf(b1.y, swr[(k)+1].y, z1);        \
  z2 = fmaf(b1.z, swr[(k)+1].z, z2); z3 = fmaf(b1.w, swr[(k)+1].w, z3);        \
  z0 = fmaf(b2.x, swr[(k)+2].x, z0); z1 = fmaf(b2.y, swr[(k)+2].y, z1);        \
  z2 = fmaf(b2.z, swr[(k)+2].z, z2); z3 = fmaf(b2.w, swr[(k)+2].w, z3);        \
  z0 = fmaf(b3.x, swr[(k)+3].x, z0); z1 = fmaf(b3.y, swr[(k)+3].y, z1);        \
  z2 = fmaf(b3.z, swr[(k)+3].z, z2); z3 = fmaf(b3.w, swr[(k)+3].w, z3);

// ---------------- main kernel: wave-cooperative, Sw resident in VGPRs --------
// lane = 16*g + c : c = channel (0..15), g = 64-float x-segment (0..3).
// Phase A: 32 rows; per row 64 FMA/lane vs register-resident Sw, x via
//          broadcast float4 loads; z folded over g with 2 shuffles -> LDS.
// Phase B: one lane per row, straight-line epilogue (normalizations folded out:
//          U2 is orthogonal and the final P-normalization is scale-invariant).
__global__ __launch_bounds__(64, 4) void hadamard_main_kernel(
    const float* __restrict__ x, const float* __restrict__ ws,
    float* __restrict__ out) {
  __shared__ __align__(16) float zlds[NR * ZSTRIDE];
  const int lane = threadIdx.x;
  const int c = lane & 15;
  const int g = lane >> 4;
  const int rb = blockIdx.x * NR;

  // Sw fragment for (channel c, segment g): 16 float4 in registers, reused 32x
  const float4* __restrict__ swv = (const float4*)ws;
  float4 swr[16];
#pragma unroll
  for (int k = 0; k < 16; ++k) swr[k] = swv[c * 64 + g * 16 + k];

  const float4* __restrict__ xv = (const float4*)x;
  const float4* p = xv + (size_t)rb * 64 + g * 16;

  // prime: row 0, chunk 0
  float4 A0 = p[0], A1 = p[1], A2 = p[2], A3 = p[3];

#pragma unroll 1
  for (int r = 0; r < NR; ++r) {
    float z0 = 0.f, z1 = 0.f, z2 = 0.f, z3 = 0.f;
    float4 B0, B1, B2, B3;
    // q0: compute A vs swr[0..3], prefetch q1 -> B
    B0 = p[4]; B1 = p[5]; B2 = p[6]; B3 = p[7];
    CHUNK(A0, A1, A2, A3, 0)
    // q1: compute B, prefetch q2 -> A
    A0 = p[8]; A1 = p[9]; A2 = p[10]; A3 = p[11];
    CHUNK(B0, B1, B2, B3, 4)
    // q2: compute A, prefetch q3 -> B
    B0 = p[12]; B1 = p[13]; B2 = p[14]; B3 = p[15];
    CHUNK(A0, A1, A2, A3, 8)
    // q3: prefetch next row's q0 -> A, compute B
    if (r < NR - 1) { A0 = p[64]; A1 = p[65]; A2 = p[66]; A3 = p[67]; }
    CHUNK(B0, B1, B2, B3, 12)

    float zr = (z0 + z1) + (z2 + z3);
    zr += __shfl_xor(zr, 16);
    zr += __shfl_xor(zr, 32);
    if (g == 0) zlds[r * ZSTRIDE + c] = zr;
    p += 64;
  }

  __syncthreads();  // single-wave block: cheap; orders ds_write -> ds_read

  if (lane < NR) {
    const int row = rb + lane;
    const float4* __restrict__ zl = (const float4*)&zlds[lane * ZSTRIDE];
    const float4 zq0 = zl[0], zq1 = zl[1], zq2 = zl[2], zq3 = zl[3];

    float f[16];
    f[0] = silu_g(zq0.x);  f[1] = silu_g(zq0.y);  f[2] = silu_g(zq0.z);  f[3] = silu_g(zq0.w);
    f[4] = silu_g(zq1.x);  f[5] = silu_g(zq1.y);  f[6] = silu_g(zq1.z);  f[7] = silu_g(zq1.w);
    f[8] = silu_g(zq2.x);  f[9] = silu_g(zq2.y);  f[10] = silu_g(zq2.z); f[11] = silu_g(zq2.w);
    f[12] = silu_g(zq3.x); f[13] = silu_g(zq3.y); f[14] = silu_g(zq3.z); f[15] = silu_g(zq3.w);

    // T = f @ U2 (unnormalized; U2 orthogonal => scale cancels in P)
    const float4* __restrict__ u2v = (const float4*)(ws + U2_OFF);
    float4 T0 = make_float4(0.f, 0.f, 0.f, 0.f);
    float4 T1 = T0, T2 = T0, T3 = T0;
#pragma unroll
    for (int cc = 0; cc < 16; ++cc) {
      const float fc = f[cc];
      const float4 u0 = u2v[cc * 4 + 0];
      const float4 u1 = u2v[cc * 4 + 1];
      const float4 u2q = u2v[cc * 4 + 2];
      const float4 u3 = u2v[cc * 4 + 3];
      T0.x = fmaf(fc, u0.x, T0.x); T0.y = fmaf(fc, u0.y, T0.y);
      T0.z = fmaf(fc, u0.z, T0.z); T0.w = fmaf(fc, u0.w, T0.w);
      T1.x = fmaf(fc, u1.x, T1.x); T1.y = fmaf(fc, u1.y, T1.y);
      T1.z = fmaf(fc, u1.z, T1.z); T1.w = fmaf(fc, u1.w, T1.w);
      T2.x = fmaf(fc, u2q.x, T2.x); T2.y = fmaf(fc, u2q.y, T2.y);
      T2.z = fmaf(fc, u2q.z, T2.z); T2.w = fmaf(fc, u2q.w, T2.w);
      T3.x = fmaf(fc, u3.x, T3.x); T3.y = fmaf(fc, u3.y, T3.y);
      T3.z = fmaf(fc, u3.z, T3.z); T3.w = fmaf(fc, u3.w, T3.w);
    }

    // e[t] = T[t]^2 + T[t+8]^2 ; P = e / sum(e)  (all upstream scales cancel)
    float e0 = fmaf(T0.x, T0.x, T2.x * T2.x);
    float e1 = fmaf(T0.y, T0.y, T2.y * T2.y);
    float e2 = fmaf(T0.z, T0.z, T2.z * T2.z);
    float e3 = fmaf(T0.w, T0.w, T2.w * T2.w);
    float e4 = fmaf(T1.x, T1.x, T3.x * T3.x);
    float e5 = fmaf(T1.y, T1.y, T3.y * T3.y);
    float e6 = fmaf(T1.z, T1.z, T3.z * T3.z);
    float e7 = fmaf(T1.w, T1.w, T3.w * T3.w);
    const float es = ((e0 + e1) + (e2 + e3)) + ((e4 + e5) + (e6 + e7));
    const float rinv = 1.f / fmaxf(es, 1e-35f);

    const float P0 = e0 * rinv, P1 = e1 * rinv, P2 = e2 * rinv, P3 = e3 * rinv;
    const float P4 = e4 * rinv, P5 = e5 * rinv, P6 = e6 * rinv, P7 = e7 * rinv;

    float4* o0 = (float4*)(out + (size_t)row * 8);
    o0[0] = make_float4(__logf(fmaxf(P0, 1e-12f)), __logf(fmaxf(P1, 1e-12f)),
                        __logf(fmaxf(P2, 1e-12f)), __logf(fmaxf(P3, 1e-12f)));
    o0[1] = make_float4(__logf(fmaxf(P4, 1e-12f)), __logf(fmaxf(P5, 1e-12f)),
                        __logf(fmaxf(P6, 1e-12f)), __logf(fmaxf(P7, 1e-12f)));
    float4* o1 = (float4*)(out + (size_t)N_ROWS * 8 + (size_t)row * 8);
    o1[0] = make_float4(P0, P1, P2, P3);
    o1[1] = make_float4(P4, P5, P6, P7);
  }
}

extern "C" void kernel_launch(void* const* d_in, const int* in_sizes, int n_in,
                              void* d_out, int out_size, void* d_ws, size_t ws_size,
                              hipStream_t stream) {
  const float* x = (const float*)d_in[0];
  const float* thc = (const float*)d_in[1];
  const float* th2 = (const float*)d_in[2];
  float* out = (float*)d_out;
  float* ws = (float*)d_ws;

  build_states_kernel<<<17, 64, 0, stream>>>(thc, th2, ws);
  hadamard_main_kernel<<<N_ROWS / NR, 64, 0, stream>>>(x, ws, out);
}

// Round 4
// 70.600 us; speedup vs baseline: 2.8544x; 2.8544x over previous
//
#include <hip/hip_runtime.h>
#include <math.h>

#define N_ROWS 131072
#define U2_OFF 4096   // floats: Sw = ws[0..4095] (16x256), U2 = ws[4096..4351] (16x16)
#define NRB 32        // rows per block (4 waves x 8 rows)
#define RPW 8         // rows per wave
#define ZST 20        // z-buffer row stride (floats)

// ---------------- stage-1 builder: 8-qubit state, 4 amps/lane ----------------
__device__ __forceinline__ void ry8(float v[4], int lane, int bp, float c, float s) {
  if (bp == 0) {
    float n0 = fmaf(s, v[1], c * v[0]);
    float n1 = fmaf(-s, v[0], c * v[1]);
    float n2 = fmaf(s, v[3], c * v[2]);
    float n3 = fmaf(-s, v[2], c * v[3]);
    v[0] = n0; v[1] = n1; v[2] = n2; v[3] = n3;
  } else if (bp == 1) {
    float n0 = fmaf(s, v[2], c * v[0]);
    float n2 = fmaf(-s, v[0], c * v[2]);
    float n1 = fmaf(s, v[3], c * v[1]);
    float n3 = fmaf(-s, v[1], c * v[3]);
    v[0] = n0; v[1] = n1; v[2] = n2; v[3] = n3;
  } else {
    int lm = 1 << (bp - 2);
    float sgn = ((lane >> (bp - 2)) & 1) ? -s : s;
#pragma unroll
    for (int k = 0; k < 4; ++k) {
      float o = __shfl_xor(v[k], lm);
      v[k] = fmaf(sgn, o, c * v[k]);
    }
  }
}

__device__ __forceinline__ void cnot8(float v[4], int lane, int cb, int tb) {
  if (cb >= 2 && tb >= 2) {
    int lm = 1 << (tb - 2);
    bool hc = (lane >> (cb - 2)) & 1;
#pragma unroll
    for (int k = 0; k < 4; ++k) {
      float o = __shfl_xor(v[k], lm);
      v[k] = hc ? o : v[k];
    }
  } else if (cb >= 2) {
    bool hc = (lane >> (cb - 2)) & 1;
    if (tb == 0) {
      float n0 = hc ? v[1] : v[0], n1 = hc ? v[0] : v[1];
      float n2 = hc ? v[3] : v[2], n3 = hc ? v[2] : v[3];
      v[0] = n0; v[1] = n1; v[2] = n2; v[3] = n3;
    } else {
      float n0 = hc ? v[2] : v[0], n2 = hc ? v[0] : v[2];
      float n1 = hc ? v[3] : v[1], n3 = hc ? v[1] : v[3];
      v[0] = n0; v[1] = n1; v[2] = n2; v[3] = n3;
    }
  } else if (tb >= 2) {
    int lm = 1 << (tb - 2);
#pragma unroll
    for (int k = 0; k < 4; ++k) {
      float o = __shfl_xor(v[k], lm);
      if ((k >> cb) & 1) v[k] = o;
    }
  } else {
    if (cb == 0) { float t = v[1]; v[1] = v[3]; v[3] = t; }
    else         { float t = v[2]; v[2] = v[3]; v[3] = t; }
  }
}

// ---------------- stage-2 builder: full 16-dim state in registers ----------------
template <int BP>
__device__ __forceinline__ void ry16t(float* w, float c, float s) {
#pragma unroll
  for (int i = 0; i < 16; ++i) {
    if (((i >> BP) & 1) == 0) {
      const int j = i | (1 << BP);
      float a = w[i], b = w[j];
      w[i] = fmaf(s, b, c * a);
      w[j] = fmaf(-s, a, c * b);
    }
  }
}
__device__ __forceinline__ void ry16(float* w, int bp, float c, float s) {
  switch (bp) {
    case 0: ry16t<0>(w, c, s); break;
    case 1: ry16t<1>(w, c, s); break;
    case 2: ry16t<2>(w, c, s); break;
    default: ry16t<3>(w, c, s); break;
  }
}
template <int CB, int TB>
__device__ __forceinline__ void cnot16t(float* w) {
#pragma unroll
  for (int i = 0; i < 16; ++i) {
    if (((i >> CB) & 1) == 1 && ((i >> TB) & 1) == 0) {
      const int j = i | (1 << TB);
      float t = w[i]; w[i] = w[j]; w[j] = t;
    }
  }
}
__device__ __forceinline__ void cnot16(float* w, int cb, int tb) {
#define CC(a, b) if (cb == a && tb == b) { cnot16t<a, b>(w); return; }
  CC(0,1) CC(0,2) CC(0,3) CC(1,0) CC(1,2) CC(1,3)
  CC(2,0) CC(2,1) CC(2,3) CC(3,0) CC(3,1) CC(3,2)
#undef CC
}

__global__ void build_states_kernel(const float* __restrict__ thc,
                                    const float* __restrict__ th2,
                                    float* __restrict__ ws) {
  const int blk = blockIdx.x;
  const int lane = threadIdx.x;  // 64 threads
  if (blk < 16) {
    const float* th = thc + blk * 72;
    float v[4] = {0.f, 0.f, 0.f, 0.f};
    if (lane == 0) v[0] = 1.f;
    int p = 0;
    for (int m = 0; m < 8; ++m) {
#pragma unroll
      for (int q = 0; q < 8; ++q) {
        float a = 0.5f * th[p + q];
        ry8(v, lane, 7 - q, cosf(a), sinf(a));
      }
      p += 8;
#pragma unroll
      for (int q = 0; q < 8; ++q) {
        int tgt = (m % 2 == 0) ? ((q + 1) & 7) : ((q + 7) & 7);
        cnot8(v, lane, 7 - q, 7 - tgt);
      }
    }
#pragma unroll
    for (int q = 0; q < 8; ++q) {
      float a = 0.5f * th[p + q];
      ry8(v, lane, 7 - q, cosf(a), sinf(a));
    }
    float4* swv = (float4*)ws;
    swv[blk * 64 + lane] = make_float4(v[0], v[1], v[2], v[3]);
  } else {
    float w[16];
#pragma unroll
    for (int j = 0; j < 16; ++j) w[j] = (j == lane) ? 1.f : 0.f;
    int p = 0;
    for (int m = 0; m < 8; ++m) {
#pragma unroll
      for (int q = 0; q < 4; ++q) {
        float a = 0.5f * th2[p + q];
        ry16(w, 3 - q, cosf(a), sinf(a));
      }
      p += 4;
#pragma unroll
      for (int q = 0; q < 4; ++q) {
        int tgt = (m % 2 == 0) ? ((q + 1) & 3) : ((q + 3) & 3);
        cnot16(w, 3 - q, 3 - tgt);
      }
    }
#pragma unroll
    for (int q = 0; q < 4; ++q) {
      float a = 0.5f * th2[p + q];
      ry16(w, 3 - q, cosf(a), sinf(a));
    }
    if (lane < 16) {
      float* u2 = ws + U2_OFF;
#pragma unroll
      for (int j = 0; j < 16; ++j) u2[lane * 16 + j] = w[j];
    }
  }
}

__device__ __forceinline__ float silu_g(float z) {
  float v = z / (1.f + __expf(-z));
  return isfinite(v) ? v : 0.f;
}

// Swizzle for the LDS x-tile (float4 index k in 0..63, row r in 0..7):
//   slot = k ^ 2*(k>>4) ^ r      (involution; (k>>4) unchanged by the XORs)
// - staging source stays within 128B lines -> coalescing preserved
// - per read instruction the 4 g-addresses land on 4 distinct bank quads
__device__ __forceinline__ int swz(int k, int r) {
  return k ^ ((k >> 4) << 1) ^ r;
}

// ---------------- main kernel ----------------
// Block = 256 thr = 4 waves; each wave owns 8 consecutive rows (no inter-wave
// sync at all). Per wave: stage 8 rows coalesced global->LDS (swizzled), then
// lane=(c,g) computes z[c] vs register-resident Sw via broadcast ds_read_b128;
// fold over g with 2 shuffles; lanes 0..7 run the per-row epilogue
// (normalizations folded out: U2 orthogonal, final P-norm scale-invariant).
__global__ __launch_bounds__(256, 4) void hadamard_main_kernel(
    const float* __restrict__ x, const float* __restrict__ ws,
    float* __restrict__ out) {
  __shared__ __align__(16) float4 xt[NRB * 64];      // 32 KB
  __shared__ __align__(16) float zb[4 * RPW * ZST];  // 2.5 KB

  const int t = threadIdx.x;
  const int w = t >> 6;
  const int lane = t & 63;
  const int c = lane & 15;
  const int g = lane >> 4;
  const int rb = blockIdx.x * NRB + w * RPW;  // this wave's first row

  // Sw fragment for (channel c, segment g): 16 float4, reused for 8 rows
  const float4* __restrict__ swv = (const float4*)ws;
  float4 swr[16];
#pragma unroll
  for (int k = 0; k < 16; ++k) swr[k] = swv[c * 64 + g * 16 + k];

  // ---- stage 8 rows into LDS (coalesced, swizzled) ----
  const float4* __restrict__ xsrc = (const float4*)x + (size_t)rb * 64;
  float4 st[RPW];
#pragma unroll
  for (int i = 0; i < RPW; ++i) st[i] = xsrc[(size_t)i * 64 + swz(lane, i)];
  float4* xw = xt + w * (RPW * 64);
#pragma unroll
  for (int i = 0; i < RPW; ++i) xw[i * 64 + lane] = st[i];

  // ---- per-row dot products vs register Sw ----
  float* zw = zb + w * (RPW * ZST);
#pragma unroll 1
  for (int r = 0; r < RPW; ++r) {
    const float4* xr = xw + r * 64;
    float z0 = 0.f, z1 = 0.f, z2 = 0.f, z3 = 0.f;
#pragma unroll
    for (int j = 0; j < 16; ++j) {
      const float4 xv4 = xr[swz(g * 16 + j, r)];
      z0 = fmaf(xv4.x, swr[j].x, z0);
      z1 = fmaf(xv4.y, swr[j].y, z1);
      z2 = fmaf(xv4.z, swr[j].z, z2);
      z3 = fmaf(xv4.w, swr[j].w, z3);
    }
    float zr_ = (z0 + z1) + (z2 + z3);
    zr_ += __shfl_xor(zr_, 16);   // fold g-pairs
    zr_ += __shfl_xor(zr_, 32);
    if (g == 0) zw[r * ZST + c] = zr_;
  }

  // ---- per-row epilogue: lanes 0..7 each own one of this wave's rows ----
  if (lane < RPW) {
    const int row = rb + lane;
    const float4* __restrict__ zl = (const float4*)&zw[lane * ZST];
    const float4 zq0 = zl[0], zq1 = zl[1], zq2 = zl[2], zq3 = zl[3];

    float f[16];
    f[0] = silu_g(zq0.x);  f[1] = silu_g(zq0.y);  f[2] = silu_g(zq0.z);  f[3] = silu_g(zq0.w);
    f[4] = silu_g(zq1.x);  f[5] = silu_g(zq1.y);  f[6] = silu_g(zq1.z);  f[7] = silu_g(zq1.w);
    f[8] = silu_g(zq2.x);  f[9] = silu_g(zq2.y);  f[10] = silu_g(zq2.z); f[11] = silu_g(zq2.w);
    f[12] = silu_g(zq3.x); f[13] = silu_g(zq3.y); f[14] = silu_g(zq3.z); f[15] = silu_g(zq3.w);

    // T = f @ U2 (unnormalized; U2 orthogonal => scale cancels in P)
    const float4* __restrict__ u2v = (const float4*)(ws + U2_OFF);
    float4 T0 = make_float4(0.f, 0.f, 0.f, 0.f);
    float4 T1 = T0, T2 = T0, T3 = T0;
#pragma unroll
    for (int cc = 0; cc < 16; ++cc) {
      const float fc = f[cc];
      const float4 u0 = u2v[cc * 4 + 0];
      const float4 u1 = u2v[cc * 4 + 1];
      const float4 u2q = u2v[cc * 4 + 2];
      const float4 u3 = u2v[cc * 4 + 3];
      T0.x = fmaf(fc, u0.x, T0.x); T0.y = fmaf(fc, u0.y, T0.y);
      T0.z = fmaf(fc, u0.z, T0.z); T0.w = fmaf(fc, u0.w, T0.w);
      T1.x = fmaf(fc, u1.x, T1.x); T1.y = fmaf(fc, u1.y, T1.y);
      T1.z = fmaf(fc, u1.z, T1.z); T1.w = fmaf(fc, u1.w, T1.w);
      T2.x = fmaf(fc, u2q.x, T2.x); T2.y = fmaf(fc, u2q.y, T2.y);
      T2.z = fmaf(fc, u2q.z, T2.z); T2.w = fmaf(fc, u2q.w, T2.w);
      T3.x = fmaf(fc, u3.x, T3.x); T3.y = fmaf(fc, u3.y, T3.y);
      T3.z = fmaf(fc, u3.z, T3.z); T3.w = fmaf(fc, u3.w, T3.w);
    }

    // e[t] = T[t]^2 + T[t+8]^2 ; P = e / sum(e)
    float e0 = fmaf(T0.x, T0.x, T2.x * T2.x);
    float e1 = fmaf(T0.y, T0.y, T2.y * T2.y);
    float e2 = fmaf(T0.z, T0.z, T2.z * T2.z);
    float e3 = fmaf(T0.w, T0.w, T2.w * T2.w);
    float e4 = fmaf(T1.x, T1.x, T3.x * T3.x);
    float e5 = fmaf(T1.y, T1.y, T3.y * T3.y);
    float e6 = fmaf(T1.z, T1.z, T3.z * T3.z);
    float e7 = fmaf(T1.w, T1.w, T3.w * T3.w);
    const float es = ((e0 + e1) + (e2 + e3)) + ((e4 + e5) + (e6 + e7));
    const float rinv = 1.f / fmaxf(es, 1e-35f);

    const float P0 = e0 * rinv, P1 = e1 * rinv, P2 = e2 * rinv, P3 = e3 * rinv;
    const float P4 = e4 * rinv, P5 = e5 * rinv, P6 = e6 * rinv, P7 = e7 * rinv;

    float4* o0 = (float4*)(out + (size_t)row * 8);
    o0[0] = make_float4(__logf(fmaxf(P0, 1e-12f)), __logf(fmaxf(P1, 1e-12f)),
                        __logf(fmaxf(P2, 1e-12f)), __logf(fmaxf(P3, 1e-12f)));
    o0[1] = make_float4(__logf(fmaxf(P4, 1e-12f)), __logf(fmaxf(P5, 1e-12f)),
                        __logf(fmaxf(P6, 1e-12f)), __logf(fmaxf(P7, 1e-12f)));
    float4* o1 = (float4*)(out + (size_t)N_ROWS * 8 + (size_t)row * 8);
    o1[0] = make_float4(P0, P1, P2, P3);
    o1[1] = make_float4(P4, P5, P6, P7);
  }
}

extern "C" void kernel_launch(void* const* d_in, const int* in_sizes, int n_in,
                              void* d_out, int out_size, void* d_ws, size_t ws_size,
                              hipStream_t stream) {
  const float* x = (const float*)d_in[0];
  const float* thc = (const float*)d_in[1];
  const float* th2 = (const float*)d_in[2];
  float* out = (float*)d_out;
  float* ws = (float*)d_ws;

  build_states_kernel<<<17, 64, 0, stream>>>(thc, th2, ws);
  hadamard_main_kernel<<<N_ROWS / NRB, 256, 0, stream>>>(x, ws, out);
}